// Round 4
// baseline (142.264 us; speedup 1.0000x reference)
//
#include <hip/hip_runtime.h>
#include <hip/hip_bf16.h>
#include <hip/hip_cooperative_groups.h>

namespace cg = cooperative_groups;

// B=64, S=512, N=32768, D=256, H=4, HD=64, T=24, scale=1/8.
//
// Workspace layout (float offsets):
//   qu  [64][256]        @ 0       (16384)  Wq(:, :256) @ user_pref[user[b]]
//   qt  [24][256]        @ 16384   (6144)   Wq(:, 256:) @ ts[t] + bq
//   kk  [96][64]         @ 22528   (6144)   (h*24+t major) Wk @ ts + bk
//   vv  [96][64]         @ 28672   (6144)   Wv @ ts + bv
//   EU  [64][4][24]      @ 34816   (6144)   exp(scale * qu.k)
//   ET  [24][4][24]      @ 40960   (2304)   exp(scale * qt.k)
//   vWB [96x256 bf16]    @ 43264   (12288 floats) folded V*Wu in MFMA-B frag layout
#define QU_OFF   0
#define QT_OFF   16384
#define KK_OFF   22528
#define VV_OFF   28672
#define EU_OFF   34816
#define ET_OFF   40960
#define VWB_OFF  43264

typedef __attribute__((ext_vector_type(8))) short bf16x8;
typedef __attribute__((ext_vector_type(4))) float f32x4;

__device__ __forceinline__ unsigned short f2bf(float f) {
    unsigned u = __builtin_bit_cast(unsigned, f);
    return (unsigned short)((u + 0x7FFFu + ((u >> 16) & 1u)) >> 16);
}

__device__ __forceinline__ float dot4(float4 a, float4 b, float s) {
    return fmaf(a.x, b.x, fmaf(a.y, b.y, fmaf(a.z, b.z, fmaf(a.w, b.w, s))));
}

// One cooperative kernel: phase A (projections) -> sync -> phase B (folded
// tables) -> sync -> phase C (softmax + MFMA GEMM). 512 blocks x 256 thr,
// 2 blocks/CU co-resident (VGPR<=256 via launch_bounds, LDS 12KB).
__global__ __launch_bounds__(256, 2) void fused_all(
    const float* __restrict__ ts, const int* __restrict__ user,
    const float* __restrict__ user_pref,
    const float* __restrict__ Wq, const float* __restrict__ bq,
    const float* __restrict__ Wk, const float* __restrict__ bk,
    const float* __restrict__ Wv, const float* __restrict__ bv,
    const float* __restrict__ Wu, const float* __restrict__ bu,
    const int* __restrict__ hour, const int* __restrict__ hour_mask,
    float* __restrict__ ws, float* __restrict__ out)
{
    cg::grid_group grid = cg::this_grid();
    __shared__ int4 A_lds[12 * 64];           // 12 KB (phase C)
    int tid = threadIdx.x;

    // ================= phase A: 34816 dot-256 projections =================
    // wave = 4 parallel 16-lane dots; coalesced 64B/lane row reads.
    {
        int gw  = blockIdx.x * 4 + (tid >> 6);   // 0..2047
        int sub = (tid >> 4) & 3, kl = tid & 15;
        #pragma unroll
        for (int it = 0; it < 5; ++it) {
            int g = gw * 4 + sub + it * 8192;
            if (g < 34816) {
                const float* wrow; const float* x;
                float bias; float* outp;
                if (g < 16384) {                  // qu
                    int b = g >> 8, j = g & 255;
                    wrow = Wq + j * 512;
                    x = user_pref + (size_t)user[b] * 256;
                    bias = 0.f; outp = ws + QU_OFF + g;
                } else if (g < 22528) {           // qt
                    int r = g - 16384, t = r >> 8, j = r & 255;
                    wrow = Wq + j * 512 + 256; x = ts + t * 256;
                    bias = bq[j]; outp = ws + QT_OFF + r;
                } else if (g < 28672) {           // kk -> [h*24+t][hd]
                    int r = g - 22528, t = r >> 8, j = r & 255;
                    wrow = Wk + j * 256; x = ts + t * 256;
                    bias = bk[j];
                    outp = ws + KK_OFF + ((j >> 6) * 24 + t) * 64 + (j & 63);
                } else {                          // vv -> [h*24+t][hd]
                    int r = g - 28672, t = r >> 8, j = r & 255;
                    wrow = Wv + j * 256; x = ts + t * 256;
                    bias = bv[j];
                    outp = ws + VV_OFF + ((j >> 6) * 24 + t) * 64 + (j & 63);
                }
                const float4* w4 = (const float4*)(wrow + kl * 16);
                const float4* x4 = (const float4*)(x + kl * 16);
                float s = 0.f;
                #pragma unroll
                for (int i = 0; i < 4; ++i) s = dot4(w4[i], x4[i], s);
                s += __shfl_xor(s, 1);
                s += __shfl_xor(s, 2);
                s += __shfl_xor(s, 4);
                s += __shfl_xor(s, 8);
                if (kl == 0) *outp = s + bias;
            }
        }
    }
    grid.sync();

    // ================= phase B: vWB (bf16 B-frag), EU, ET =================
    {
        int o = blockIdx.x * 256 + tid;
        const float* qu = ws + QU_OFF;
        const float* qt = ws + QT_OFF;
        const float* kk = ws + KK_OFF;
        const float* vv = ws + VV_OFF;
        if (o < 12288) {                          // vWB: thread = (ht-pair, d)
            int htp = o >> 8, d = o & 255;
            int ht = htp * 2;
            int h = ht / 24;                      // pair never crosses h
            const float4* v0 = (const float4*)(vv + ht * 64);
            const float4* v1 = (const float4*)(vv + ht * 64 + 64);
            const float4* wp = (const float4*)(Wu + d * 256 + h * 64);
            float s0 = 0.f, s1 = 0.f;
            #pragma unroll
            for (int i = 0; i < 16; ++i) {
                float4 wv = wp[i];
                s0 = dot4(v0[i], wv, s0);
                s1 = dot4(v1[i], wv, s1);
            }
            // B-frag: (k=ht, col=d) -> lane=(d&15)+16*((ht>>3)&3), word (ht&7)>>1
            int kt = ht >> 5, nt = d >> 4, lg = (ht >> 3) & 3, jh = (ht & 7) >> 1;
            unsigned pack = (unsigned)f2bf(s0) | ((unsigned)f2bf(s1) << 16);
            ((unsigned*)(ws + VWB_OFF))[(kt * 16 + nt) * 256 + ((d & 15) + 16 * lg) * 4 + jh] = pack;
        } else if (o < 18432) {                   // EU[b][h*24+t]
            int o2 = o - 12288;
            int b = o2 / 96, rem = o2 - b * 96;
            const float4* qp = (const float4*)(qu + b * 256 + (rem / 24) * 64);
            const float4* kp = (const float4*)(kk + rem * 64);
            float s = 0.f;
            #pragma unroll
            for (int i = 0; i < 16; ++i) s = dot4(qp[i], kp[i], s);
            ws[EU_OFF + o2] = expf(s * 0.125f);
        } else if (o < 20736) {                   // ET[t'][h*24+t]
            int o3 = o - 18432;
            int tp = o3 / 96, rem = o3 - tp * 96;
            const float4* qp = (const float4*)(qt + tp * 256 + (rem / 24) * 64);
            const float4* kp = (const float4*)(kk + rem * 64);
            float s = 0.f;
            #pragma unroll
            for (int i = 0; i < 16; ++i) s = dot4(qp[i], kp[i], s);
            ws[ET_OFF + o3] = expf(s * 0.125f);
        }
    }
    grid.sync();

    // ========= phase C: softmax (no exp) -> A-frags -> MFMA GEMM =========
    {
        const float* EU = ws + EU_OFF;
        const float* ET = ws + ET_OFF;
        int nb = blockIdx.x * 64;                 // 64 tokens/block, same b
        int b = nb >> 9;
        // phase C1: attention probs, thread = (tok, h); bf16 A-fragments
        {
            int tok = tid >> 2, h = tid & 3;
            int n = nb + tok;
            int th = hour[n];
            const float4* EUp = (const float4*)(EU + b * 96 + h * 24);
            const float4* ETp = (const float4*)(ET + th * 96 + h * 24);
            const int4*   mp  = (const int4*)(hour_mask + (long long)n * 24);
            float p[24]; float ssum = 0.f;
            #pragma unroll
            for (int q = 0; q < 6; ++q) {
                float4 e = EUp[q]; float4 f = ETp[q]; int4 m = mp[q];
                float v0 = (m.x != 0) ? 0.f : e.x * f.x;
                float v1 = (m.y != 0) ? 0.f : e.y * f.y;
                float v2 = (m.z != 0) ? 0.f : e.z * f.z;
                float v3 = (m.w != 0) ? 0.f : e.w * f.w;
                p[q*4+0] = v0; p[q*4+1] = v1; p[q*4+2] = v2; p[q*4+3] = v3;
                ssum += (v0 + v1) + (v2 + v3);
            }
            float r = 1.0f / ssum;
            int mt = tok >> 4, tl = tok & 15;
            #pragma unroll
            for (int tp = 0; tp < 12; ++tp) {
                int ht = h * 24 + tp * 2;         // even; pair (ht, ht+1)
                unsigned pack = (unsigned)f2bf(p[tp*2] * r)
                              | ((unsigned)f2bf(p[tp*2+1] * r) << 16);
                int kt = ht >> 5, lg = (ht >> 3) & 3, jh = (ht & 7) >> 1;
                ((unsigned*)A_lds)[((kt * 4 + mt) * 64 + tl + 16 * lg) * 4 + jh] = pack;
            }
        }
        __syncthreads();
        // phase C2: wave w: 4 M-tiles x 4 N-tiles x 3 K-chunks of 16x16x32
        int w = tid >> 6, l = tid & 63;
        const int4* Bg = (const int4*)(ws + VWB_OFF);
        bf16x8 afr[3][4], bfr[3][4];
        #pragma unroll
        for (int kt = 0; kt < 3; ++kt)
            #pragma unroll
            for (int q = 0; q < 4; ++q) {
                afr[kt][q] = __builtin_bit_cast(bf16x8, A_lds[(kt * 4 + q) * 64 + l]);
                bfr[kt][q] = __builtin_bit_cast(bf16x8, Bg[(kt * 16 + w * 4 + q) * 64 + l]);
            }
        f32x4 acc[4][4];
        #pragma unroll
        for (int mt = 0; mt < 4; ++mt)
            #pragma unroll
            for (int q = 0; q < 4; ++q) acc[mt][q] = (f32x4)0.f;
        #pragma unroll
        for (int kt = 0; kt < 3; ++kt)
            #pragma unroll
            for (int mt = 0; mt < 4; ++mt)
                #pragma unroll
                for (int q = 0; q < 4; ++q)
                    acc[mt][q] = __builtin_amdgcn_mfma_f32_16x16x32_bf16(
                        afr[kt][mt], bfr[kt][q], acc[mt][q], 0, 0, 0);
        // epilogue: + bu, store (D: col=l&15, row=(l>>4)*4+reg)
        int colb = w * 64 + (l & 15);
        float buv[4];
        #pragma unroll
        for (int q = 0; q < 4; ++q) buv[q] = bu[colb + q * 16];
        int row0 = nb + (l >> 4) * 4;
        #pragma unroll
        for (int mt = 0; mt < 4; ++mt)
            #pragma unroll
            for (int q = 0; q < 4; ++q) {
                float* op = out + (size_t)(row0 + mt * 16) * 256 + colb + q * 16;
                #pragma unroll
                for (int r = 0; r < 4; ++r)
                    op[(size_t)r * 256] = acc[mt][q][r] + buv[q];
            }
    }
}

extern "C" void kernel_launch(void* const* d_in, const int* in_sizes, int n_in,
                              void* d_out, int out_size, void* d_ws, size_t ws_size,
                              hipStream_t stream)
{
    const float* ts        = (const float*)d_in[0];
    const int*   user      = (const int*)  d_in[1];
    const int*   hour      = (const int*)  d_in[2];
    const int*   hour_mask = (const int*)  d_in[3];
    const float* user_pref = (const float*)d_in[4];
    const float* Wq        = (const float*)d_in[5];
    const float* bq        = (const float*)d_in[6];
    const float* Wk        = (const float*)d_in[7];
    const float* bk        = (const float*)d_in[8];
    const float* Wv        = (const float*)d_in[9];
    const float* bv        = (const float*)d_in[10];
    const float* Wu        = (const float*)d_in[11];
    const float* bu        = (const float*)d_in[12];
    float* ws  = (float*)d_ws;
    float* out = (float*)d_out;

    void* args[] = {
        (void*)&ts, (void*)&user, (void*)&user_pref,
        (void*)&Wq, (void*)&bq, (void*)&Wk, (void*)&bk,
        (void*)&Wv, (void*)&bv, (void*)&Wu, (void*)&bu,
        (void*)&hour, (void*)&hour_mask, (void*)&ws, (void*)&out
    };
    hipLaunchCooperativeKernel((const void*)fused_all, dim3(512), dim3(256),
                               args, 0, stream);
}

// Round 5
// 115.101 us; speedup vs baseline: 1.2360x; 1.2360x over previous
//
#include <hip/hip_runtime.h>
#include <hip/hip_bf16.h>

// B=64, S=512, N=32768, D=256, H=4, HD=64, T=24, scale=1/8.
//
// Workspace layout (float offsets):
//   qu  [64][256]        @ 0       (16384)  Wq(:, :256) @ user_pref[user[b]]
//   qt  [24][256]        @ 16384   (6144)   Wq(:, 256:) @ ts[t] + bq
//   kk  [96][64]         @ 22528   (6144)   (h*24+t major) Wk @ ts + bk
//   vv  [96][64]         @ 28672   (6144)   Wv @ ts + bv
//   EU  [64][4][24]      @ 34816   (6144)   exp(scale * qu.k)
//   ET  [24][4][24]      @ 40960   (2304)   exp(scale * qt.k)
//   vWB [96x256 bf16]    @ 43264   (12288 floats) folded V*Wu in MFMA-B frag layout
//   bar [2 x u32]        @ 55552   grid-barrier counters (memset to 0 per call)
#define QU_OFF   0
#define QT_OFF   16384
#define KK_OFF   22528
#define VV_OFF   28672
#define EU_OFF   34816
#define ET_OFF   40960
#define VWB_OFF  43264
#define BAR_OFF  55552
#define NBLK     512u

typedef __attribute__((ext_vector_type(8))) short bf16x8;
typedef __attribute__((ext_vector_type(4))) float f32x4;

__device__ __forceinline__ unsigned short f2bf(float f) {
    unsigned u = __builtin_bit_cast(unsigned, f);
    return (unsigned short)((u + 0x7FFFu + ((u >> 16) & 1u)) >> 16);
}

__device__ __forceinline__ float dot4(float4 a, float4 b, float s) {
    return fmaf(a.x, b.x, fmaf(a.y, b.y, fmaf(a.z, b.z, fmaf(a.w, b.w, s))));
}

// Hand-rolled grid barrier (agent scope). All blocks co-resident via
// cooperative launch; release-RMW publishes this block's ws writes to the
// IF$/common point, acquire-load invalidates stale L1/L2 before readers.
__device__ __forceinline__ void gbar(unsigned* ctr) {
    __syncthreads();
    if (threadIdx.x == 0) {
        __hip_atomic_fetch_add(ctr, 1u, __ATOMIC_RELEASE, __HIP_MEMORY_SCOPE_AGENT);
        while (__hip_atomic_load(ctr, __ATOMIC_RELAXED, __HIP_MEMORY_SCOPE_AGENT) < NBLK)
            __builtin_amdgcn_s_sleep(2);
        (void)__hip_atomic_load(ctr, __ATOMIC_ACQUIRE, __HIP_MEMORY_SCOPE_AGENT);
    }
    __syncthreads();
}

__global__ __launch_bounds__(256, 2) void fused_all(
    const float* __restrict__ ts, const int* __restrict__ user,
    const float* __restrict__ user_pref,
    const float* __restrict__ Wq, const float* __restrict__ bq,
    const float* __restrict__ Wk, const float* __restrict__ bk,
    const float* __restrict__ Wv, const float* __restrict__ bv,
    const float* __restrict__ Wu, const float* __restrict__ bu,
    const int* __restrict__ hour, const int* __restrict__ hour_mask,
    float* __restrict__ ws, float* __restrict__ out)
{
    __shared__ int4 A_lds[12 * 64];           // 12 KB (phase C)
    int tid = threadIdx.x;
    unsigned* bar = (unsigned*)(ws + BAR_OFF);

    // ================= phase A: 34816 dot-256 projections =================
    {
        int gw  = blockIdx.x * 4 + (tid >> 6);   // 0..2047
        int sub = (tid >> 4) & 3, kl = tid & 15;
        #pragma unroll
        for (int it = 0; it < 5; ++it) {
            int g = gw * 4 + sub + it * 8192;
            if (g < 34816) {
                const float* wrow; const float* x;
                float bias; float* outp;
                if (g < 16384) {                  // qu
                    int b = g >> 8, j = g & 255;
                    wrow = Wq + j * 512;
                    x = user_pref + (size_t)user[b] * 256;
                    bias = 0.f; outp = ws + QU_OFF + g;
                } else if (g < 22528) {           // qt
                    int r = g - 16384, t = r >> 8, j = r & 255;
                    wrow = Wq + j * 512 + 256; x = ts + t * 256;
                    bias = bq[j]; outp = ws + QT_OFF + r;
                } else if (g < 28672) {           // kk -> [h*24+t][hd]
                    int r = g - 22528, t = r >> 8, j = r & 255;
                    wrow = Wk + j * 256; x = ts + t * 256;
                    bias = bk[j];
                    outp = ws + KK_OFF + ((j >> 6) * 24 + t) * 64 + (j & 63);
                } else {                          // vv -> [h*24+t][hd]
                    int r = g - 28672, t = r >> 8, j = r & 255;
                    wrow = Wv + j * 256; x = ts + t * 256;
                    bias = bv[j];
                    outp = ws + VV_OFF + ((j >> 6) * 24 + t) * 64 + (j & 63);
                }
                const float4* w4 = (const float4*)(wrow + kl * 16);
                const float4* x4 = (const float4*)(x + kl * 16);
                float s = 0.f;
                #pragma unroll
                for (int i = 0; i < 4; ++i) s = dot4(w4[i], x4[i], s);
                s += __shfl_xor(s, 1);
                s += __shfl_xor(s, 2);
                s += __shfl_xor(s, 4);
                s += __shfl_xor(s, 8);
                if (kl == 0) *outp = s + bias;
            }
        }
    }
    gbar(&bar[0]);

    // ================= phase B: vWB (bf16 B-frag), EU, ET =================
    {
        int o = blockIdx.x * 256 + tid;
        const float* qu = ws + QU_OFF;
        const float* qt = ws + QT_OFF;
        const float* kk = ws + KK_OFF;
        const float* vv = ws + VV_OFF;
        if (o < 12288) {                          // vWB: thread = (ht-pair, d)
            int htp = o >> 8, d = o & 255;
            int ht = htp * 2;
            int h = ht / 24;                      // pair never crosses h
            const float4* v0 = (const float4*)(vv + ht * 64);
            const float4* v1 = (const float4*)(vv + ht * 64 + 64);
            const float4* wp = (const float4*)(Wu + d * 256 + h * 64);
            float s0 = 0.f, s1 = 0.f;
            #pragma unroll
            for (int i = 0; i < 16; ++i) {
                float4 wv = wp[i];
                s0 = dot4(v0[i], wv, s0);
                s1 = dot4(v1[i], wv, s1);
            }
            // B-frag: (k=ht, col=d) -> lane=(d&15)+16*((ht>>3)&3), word (ht&7)>>1
            int kt = ht >> 5, nt = d >> 4, lg = (ht >> 3) & 3, jh = (ht & 7) >> 1;
            unsigned pack = (unsigned)f2bf(s0) | ((unsigned)f2bf(s1) << 16);
            ((unsigned*)(ws + VWB_OFF))[(kt * 16 + nt) * 256 + ((d & 15) + 16 * lg) * 4 + jh] = pack;
        } else if (o < 18432) {                   // EU[b][h*24+t]
            int o2 = o - 12288;
            int b = o2 / 96, rem = o2 - b * 96;
            const float4* qp = (const float4*)(qu + b * 256 + (rem / 24) * 64);
            const float4* kp = (const float4*)(kk + rem * 64);
            float s = 0.f;
            #pragma unroll
            for (int i = 0; i < 16; ++i) s = dot4(qp[i], kp[i], s);
            ws[EU_OFF + o2] = expf(s * 0.125f);
        } else if (o < 20736) {                   // ET[t'][h*24+t]
            int o3 = o - 18432;
            int tp = o3 / 96, rem = o3 - tp * 96;
            const float4* qp = (const float4*)(qt + tp * 256 + (rem / 24) * 64);
            const float4* kp = (const float4*)(kk + rem * 64);
            float s = 0.f;
            #pragma unroll
            for (int i = 0; i < 16; ++i) s = dot4(qp[i], kp[i], s);
            ws[ET_OFF + o3] = expf(s * 0.125f);
        }
    }
    gbar(&bar[1]);

    // ========= phase C: softmax (no exp) -> A-frags -> MFMA GEMM =========
    {
        const float* EU = ws + EU_OFF;
        const float* ET = ws + ET_OFF;
        int nb = blockIdx.x * 64;                 // 64 tokens/block, same b
        int b = nb >> 9;
        // phase C1: attention probs, thread = (tok, h); bf16 A-fragments
        {
            int tok = tid >> 2, h = tid & 3;
            int n = nb + tok;
            int th = hour[n];
            const float4* EUp = (const float4*)(EU + b * 96 + h * 24);
            const float4* ETp = (const float4*)(ET + th * 96 + h * 24);
            const int4*   mp  = (const int4*)(hour_mask + (long long)n * 24);
            float p[24]; float ssum = 0.f;
            #pragma unroll
            for (int q = 0; q < 6; ++q) {
                float4 e = EUp[q]; float4 f = ETp[q]; int4 m = mp[q];
                float v0 = (m.x != 0) ? 0.f : e.x * f.x;
                float v1 = (m.y != 0) ? 0.f : e.y * f.y;
                float v2 = (m.z != 0) ? 0.f : e.z * f.z;
                float v3 = (m.w != 0) ? 0.f : e.w * f.w;
                p[q*4+0] = v0; p[q*4+1] = v1; p[q*4+2] = v2; p[q*4+3] = v3;
                ssum += (v0 + v1) + (v2 + v3);
            }
            float r = 1.0f / ssum;
            int mt = tok >> 4, tl = tok & 15;
            #pragma unroll
            for (int tp = 0; tp < 12; ++tp) {
                int ht = h * 24 + tp * 2;         // even; pair (ht, ht+1)
                unsigned pack = (unsigned)f2bf(p[tp*2] * r)
                              | ((unsigned)f2bf(p[tp*2+1] * r) << 16);
                int kt = ht >> 5, lg = (ht >> 3) & 3, jh = (ht & 7) >> 1;
                ((unsigned*)A_lds)[((kt * 4 + mt) * 64 + tl + 16 * lg) * 4 + jh] = pack;
            }
        }
        __syncthreads();
        // phase C2: wave w: 4 M-tiles x 4 N-tiles x 3 K-chunks of 16x16x32
        int w = tid >> 6, l = tid & 63;
        const int4* Bg = (const int4*)(ws + VWB_OFF);
        bf16x8 afr[3][4], bfr[3][4];
        #pragma unroll
        for (int kt = 0; kt < 3; ++kt)
            #pragma unroll
            for (int q = 0; q < 4; ++q) {
                afr[kt][q] = __builtin_bit_cast(bf16x8, A_lds[(kt * 4 + q) * 64 + l]);
                bfr[kt][q] = __builtin_bit_cast(bf16x8, Bg[(kt * 16 + w * 4 + q) * 64 + l]);
            }
        f32x4 acc[4][4];
        #pragma unroll
        for (int mt = 0; mt < 4; ++mt)
            #pragma unroll
            for (int q = 0; q < 4; ++q) acc[mt][q] = (f32x4)0.f;
        #pragma unroll
        for (int kt = 0; kt < 3; ++kt)
            #pragma unroll
            for (int mt = 0; mt < 4; ++mt)
                #pragma unroll
                for (int q = 0; q < 4; ++q)
                    acc[mt][q] = __builtin_amdgcn_mfma_f32_16x16x32_bf16(
                        afr[kt][mt], bfr[kt][q], acc[mt][q], 0, 0, 0);
        // epilogue: + bu, store (D: col=l&15, row=(l>>4)*4+reg)
        int colb = w * 64 + (l & 15);
        float buv[4];
        #pragma unroll
        for (int q = 0; q < 4; ++q) buv[q] = bu[colb + q * 16];
        int row0 = nb + (l >> 4) * 4;
        #pragma unroll
        for (int mt = 0; mt < 4; ++mt)
            #pragma unroll
            for (int q = 0; q < 4; ++q) {
                float* op = out + (size_t)(row0 + mt * 16) * 256 + colb + q * 16;
                #pragma unroll
                for (int r = 0; r < 4; ++r)
                    op[(size_t)r * 256] = acc[mt][q][r] + buv[q];
            }
    }
}

extern "C" void kernel_launch(void* const* d_in, const int* in_sizes, int n_in,
                              void* d_out, int out_size, void* d_ws, size_t ws_size,
                              hipStream_t stream)
{
    const float* ts        = (const float*)d_in[0];
    const int*   user      = (const int*)  d_in[1];
    const int*   hour      = (const int*)  d_in[2];
    const int*   hour_mask = (const int*)  d_in[3];
    const float* user_pref = (const float*)d_in[4];
    const float* Wq        = (const float*)d_in[5];
    const float* bq        = (const float*)d_in[6];
    const float* Wk        = (const float*)d_in[7];
    const float* bk        = (const float*)d_in[8];
    const float* Wv        = (const float*)d_in[9];
    const float* bv        = (const float*)d_in[10];
    const float* Wu        = (const float*)d_in[11];
    const float* bu        = (const float*)d_in[12];
    float* ws  = (float*)d_ws;
    float* out = (float*)d_out;

    // zero the grid-barrier counters (captured in graph; runs every replay)
    hipMemsetAsync(ws + BAR_OFF, 0, 2 * sizeof(unsigned), stream);

    void* args[] = {
        (void*)&ts, (void*)&user, (void*)&user_pref,
        (void*)&Wq, (void*)&bq, (void*)&Wk, (void*)&bk,
        (void*)&Wv, (void*)&bv, (void*)&Wu, (void*)&bu,
        (void*)&hour, (void*)&hour_mask, (void*)&ws, (void*)&out
    };
    hipLaunchCooperativeKernel((const void*)fused_all, dim3(NBLK), dim3(256),
                               args, 0, stream);
}

// Round 6
// 24.648 us; speedup vs baseline: 5.7717x; 4.6697x over previous
//
#include <hip/hip_runtime.h>
#include <hip/hip_bf16.h>

// B=64, S=512, N=32768, D=256, H=4, HD=64, T=24, scale=1/8.
//
// Workspace (float offsets):
//   qu  [64][256] f32   @ 0      (16384)
//   kk  [96][64]  f32   @ 16384  (6144)   (h*24+t, hd)
//   ET  [24][96]  f32   @ 22528  (2304)   exp(scale * qt . kk)
//   vWB 96x256 bf16     @ 24832  (12288 f32 words) folded V*Wu, MFMA-B frag layout
#define QU_OFF   0
#define KK_OFF   16384
#define ET_OFF   22528
#define VWB_OFF  24832

typedef __attribute__((ext_vector_type(8))) short bf16x8;
typedef __attribute__((ext_vector_type(4))) float f32x4;

__device__ __forceinline__ unsigned short f2bf(float f) {
    unsigned u = __builtin_bit_cast(unsigned, f);
    return (unsigned short)((u + 0x7FFFu + ((u >> 16) & 1u)) >> 16);
}
__device__ __forceinline__ unsigned packbf(float a, float b) {
    return (unsigned)f2bf(a) | ((unsigned)f2bf(b) << 16);
}
__device__ __forceinline__ bf16x8 cvt8(float4 f0, float4 f1) {
    int4 v = make_int4(packbf(f0.x, f0.y), packbf(f0.z, f0.w),
                       packbf(f1.x, f1.y), packbf(f1.z, f1.w));
    return __builtin_bit_cast(bf16x8, v);
}
__device__ __forceinline__ float dot4(float4 a, float4 b, float s) {
    return fmaf(a.x, b.x, fmaf(a.y, b.y, fmaf(a.z, b.z, fmaf(a.w, b.w, s))));
}

// Fragment conventions (validated end-to-end by the passing C2 kernel):
//   A-frag 16(m)x32(k): lane=(m&15)+16*((k>>3)&3), u32 word=(k&7)>>1, half=k&1
//   B-frag 16(n)x32(k): same with n in place of m
//   D-frag: lane l, reg r -> row=(l>>4)*4+r, col=(l&15)

// ---------- K1: all precompute, 16 independent blocks ----------
// blk 0..7 : qu quarters (q=blk>>1 -> rows b0..b0+15, nhalf=blk&1 -> 128 cols)
// blk 8..11: qk-chain h: qt_h, kk_h (MFMA) -> ET (VALU, in-LDS)
// blk 12..15: v-chain h: vv_h (MFMA) -> vW_h (MFMA) -> vWB global
__global__ __launch_bounds__(256) void precomp(
    const float* __restrict__ ts, const int* __restrict__ user,
    const float* __restrict__ user_pref,
    const float* __restrict__ Wq, const float* __restrict__ bq,
    const float* __restrict__ Wk, const float* __restrict__ bk,
    const float* __restrict__ Wv, const float* __restrict__ bv,
    const float* __restrict__ Wu, float* __restrict__ ws)
{
    __shared__ unsigned sA[4096];          // 16 KB: A-frags [(kt*2+mt)*64+lane]*4+word
    __shared__ float sM1[32 * 68];         // padded [32][68]
    __shared__ float sM2[32 * 68];
    int tid = threadIdx.x, blk = blockIdx.x;
    int w = tid >> 6, l = tid & 63;
    int eo = (l >> 4) * 8;                 // per-lane k-offset within a frag

    if (blk < 8) {
        // ================= qu = gather(user_pref) @ WqU^T =================
        int q = blk >> 1, nh = blk & 1, b0 = q * 16;
        for (int u = tid; u < 512; u += 256) {       // stage A: 16 rows
            int r = u >> 5, e0 = (u & 31) * 8;
            const float* src = user_pref + (size_t)user[b0 + r] * 256 + e0;
            float4 f0 = *(const float4*)src, f1 = *(const float4*)(src + 4);
            unsigned* dst = &sA[(((e0 >> 5) * 2) * 64 + (r & 15) + 16 * ((e0 >> 3) & 3)) * 4];
            dst[0] = packbf(f0.x, f0.y); dst[1] = packbf(f0.z, f0.w);
            dst[2] = packbf(f1.x, f1.y); dst[3] = packbf(f1.z, f1.w);
        }
        __syncthreads();
        #pragma unroll
        for (int ntq = 0; ntq < 2; ++ntq) {
            int col = nh * 128 + (w * 2 + ntq) * 16 + (l & 15);
            float4 fb[8][2];
            #pragma unroll
            for (int kt = 0; kt < 8; ++kt) {
                const float* Bp = Wq + (size_t)col * 512 + kt * 32 + eo;
                fb[kt][0] = *(const float4*)Bp; fb[kt][1] = *(const float4*)(Bp + 4);
            }
            f32x4 acc = (f32x4)0.f;
            #pragma unroll
            for (int kt = 0; kt < 8; ++kt) {
                bf16x8 afr = __builtin_bit_cast(bf16x8, *(const int4*)&sA[((kt * 2) * 64 + l) * 4]);
                acc = __builtin_amdgcn_mfma_f32_16x16x32_bf16(afr, cvt8(fb[kt][0], fb[kt][1]), acc, 0, 0, 0);
            }
            int row = (l >> 4) * 4;
            #pragma unroll
            for (int r = 0; r < 4; ++r)
                ws[QU_OFF + (size_t)(b0 + row + r) * 256 + col] = acc[r];
        }
        return;
    }

    // ---- blocks 8..15 stage ts[24][256] as A-frags (rows 24..31 unused) ----
    for (int u = tid; u < 768; u += 256) {
        int r = u >> 5, e0 = (u & 31) * 8;
        const float* src = ts + r * 256 + e0;
        float4 f0 = *(const float4*)src, f1 = *(const float4*)(src + 4);
        unsigned* dst = &sA[(((e0 >> 5) * 2 + (r >> 4)) * 64 + (r & 15) + 16 * ((e0 >> 3) & 3)) * 4];
        dst[0] = packbf(f0.x, f0.y); dst[1] = packbf(f0.z, f0.w);
        dst[2] = packbf(f1.x, f1.y); dst[3] = packbf(f1.z, f1.w);
    }
    __syncthreads();

    if (blk < 12) {
        // ============ qk-chain h: qt_h, kk_h -> ET[t'][h*24+t] ============
        int h = blk - 8;
        int j = h * 64 + w * 16 + (l & 15);          // head-dim col
        float4 fa[8][2], fc[8][2];
        #pragma unroll
        for (int kt = 0; kt < 8; ++kt) {
            const float* Bq = Wq + (size_t)j * 512 + 256 + kt * 32 + eo;
            const float* Bk = Wk + (size_t)j * 256 + kt * 32 + eo;
            fa[kt][0] = *(const float4*)Bq; fa[kt][1] = *(const float4*)(Bq + 4);
            fc[kt][0] = *(const float4*)Bk; fc[kt][1] = *(const float4*)(Bk + 4);
        }
        f32x4 aca[2] = {(f32x4)0.f, (f32x4)0.f};
        f32x4 acb[2] = {(f32x4)0.f, (f32x4)0.f};
        #pragma unroll
        for (int kt = 0; kt < 8; ++kt) {
            bf16x8 bq8 = cvt8(fa[kt][0], fa[kt][1]);
            bf16x8 bk8 = cvt8(fc[kt][0], fc[kt][1]);
            #pragma unroll
            for (int mt = 0; mt < 2; ++mt) {
                bf16x8 afr = __builtin_bit_cast(bf16x8, *(const int4*)&sA[((kt * 2 + mt) * 64 + l) * 4]);
                aca[mt] = __builtin_amdgcn_mfma_f32_16x16x32_bf16(afr, bq8, aca[mt], 0, 0, 0);
                acb[mt] = __builtin_amdgcn_mfma_f32_16x16x32_bf16(afr, bk8, acb[mt], 0, 0, 0);
            }
        }
        float bqv = bq[j], bkv = bk[j];
        int hd = w * 16 + (l & 15);
        #pragma unroll
        for (int mt = 0; mt < 2; ++mt) {
            int t0 = mt * 16 + (l >> 4) * 4;
            #pragma unroll
            for (int r = 0; r < 4; ++r) {
                int t = t0 + r;
                if (t < 24) {
                    sM1[t * 68 + hd] = aca[mt][r] + bqv;
                    float kv = acb[mt][r] + bkv;
                    sM2[t * 68 + hd] = kv;
                    ws[KK_OFF + (h * 24 + t) * 64 + hd] = kv;
                }
            }
        }
        __syncthreads();
        for (int u = tid; u < 576; u += 256) {       // ET: 24x24 dot-64
            int tp = u / 24, t = u - tp * 24;
            const float4* qp4 = (const float4*)&sM1[tp * 68];
            const float4* kp4 = (const float4*)&sM2[t * 68];
            float s = 0.f;
            #pragma unroll
            for (int i = 0; i < 16; ++i) s = dot4(qp4[i], kp4[i], s);
            ws[ET_OFF + tp * 96 + h * 24 + t] = expf(s * 0.125f);
        }
        return;
    }

    // ============== v-chain h: vv_h -> vW_h -> vWB (B-frag) ==============
    {
        int h = blk - 12;
        int jv = h * 64 + w * 16 + (l & 15);
        float4 fv[8][2];
        #pragma unroll
        for (int kt = 0; kt < 8; ++kt) {
            const float* Bv = Wv + (size_t)jv * 256 + kt * 32 + eo;
            fv[kt][0] = *(const float4*)Bv; fv[kt][1] = *(const float4*)(Bv + 4);
        }
        f32x4 acv[2] = {(f32x4)0.f, (f32x4)0.f};
        #pragma unroll
        for (int kt = 0; kt < 8; ++kt) {
            bf16x8 bv8 = cvt8(fv[kt][0], fv[kt][1]);
            #pragma unroll
            for (int mt = 0; mt < 2; ++mt) {
                bf16x8 afr = __builtin_bit_cast(bf16x8, *(const int4*)&sA[((kt * 2 + mt) * 64 + l) * 4]);
                acv[mt] = __builtin_amdgcn_mfma_f32_16x16x32_bf16(afr, bv8, acv[mt], 0, 0, 0);
            }
        }
        float bvv = bv[jv];
        int hd = w * 16 + (l & 15);
        #pragma unroll
        for (int mt = 0; mt < 2; ++mt) {
            int t0 = mt * 16 + (l >> 4) * 4;
            #pragma unroll
            for (int r = 0; r < 4; ++r)
                if (t0 + r < 24) sM1[(t0 + r) * 68 + hd] = acv[mt][r] + bvv;
        }
        __syncthreads();
        // GEMM2: vW = vv[24(p32) x 64] @ WuCols^T -> vWB, N=256, wave nt2 = w*4+q
        f32x4 ac2[2][4];
        #pragma unroll
        for (int mt = 0; mt < 2; ++mt)
            #pragma unroll
            for (int q = 0; q < 4; ++q) ac2[mt][q] = (f32x4)0.f;
        #pragma unroll
        for (int kt2 = 0; kt2 < 2; ++kt2) {
            int k0 = kt2 * 32 + eo;
            bf16x8 a2[2];
            #pragma unroll
            for (int mt = 0; mt < 2; ++mt) {
                int m = mt * 16 + (l & 15);
                float4 g0 = *(const float4*)&sM1[m * 68 + k0];
                float4 g1 = *(const float4*)&sM1[m * 68 + k0 + 4];
                a2[mt] = cvt8(g0, g1);
            }
            float4 fu[4][2];
            #pragma unroll
            for (int q = 0; q < 4; ++q) {
                int d = (w * 4 + q) * 16 + (l & 15);
                const float* Bu = Wu + (size_t)d * 256 + h * 64 + k0;
                fu[q][0] = *(const float4*)Bu; fu[q][1] = *(const float4*)(Bu + 4);
            }
            #pragma unroll
            for (int q = 0; q < 4; ++q) {
                bf16x8 bu8 = cvt8(fu[q][0], fu[q][1]);
                #pragma unroll
                for (int mt = 0; mt < 2; ++mt)
                    ac2[mt][q] = __builtin_amdgcn_mfma_f32_16x16x32_bf16(a2[mt], bu8, ac2[mt][q], 0, 0, 0);
            }
        }
        unsigned* vwb = (unsigned*)(ws + VWB_OFF);
        #pragma unroll
        for (int mt = 0; mt < 2; ++mt) {
            int t0 = mt * 16 + (l >> 4) * 4;
            if (t0 < 24) {
                #pragma unroll
                for (int q = 0; q < 4; ++q) {
                    int d = (w * 4 + q) * 16 + (l & 15);
                    #pragma unroll
                    for (int pp = 0; pp < 2; ++pp) {
                        int ht = h * 24 + t0 + pp * 2;       // even
                        unsigned pk = packbf(ac2[mt][q][pp * 2], ac2[mt][q][pp * 2 + 1]);
                        int ktC = ht >> 5, ntC = d >> 4;
                        int lgC = (ht >> 3) & 3, jhC = (ht & 7) >> 1;
                        vwb[(ktC * 16 + ntC) * 256 + ((d & 15) + 16 * lgC) * 4 + jhC] = pk;
                    }
                }
            }
        }
    }
}

// ---------- K2: EU (in-LDS) + softmax (no exp) -> A-frags -> MFMA GEMM ----------
__global__ __launch_bounds__(256) void attn_mfma(
    const int* __restrict__ hour, const int* __restrict__ hour_mask,
    const float* __restrict__ ws, const float* __restrict__ bu,
    float* __restrict__ out)
{
    const float* ET = ws + ET_OFF;
    __shared__ int4 A_lds[12 * 64];           // 12 KB
    __shared__ float EU_s[96];
    int tid = threadIdx.x;
    int nb = blockIdx.x * 64;                 // 64 tokens/block, same b
    int b = nb >> 9;
    // ---- EU[h*24+t] = exp(scale * qu[b]_h . kk[ht]) ----
    if (tid < 96) {
        const float4* qp = (const float4*)(ws + QU_OFF + b * 256 + (tid / 24) * 64);
        const float4* kp = (const float4*)(ws + KK_OFF + tid * 64);
        float s = 0.f;
        #pragma unroll
        for (int i = 0; i < 16; ++i) s = dot4(qp[i], kp[i], s);
        EU_s[tid] = expf(s * 0.125f);
    }
    __syncthreads();
    // ---- phase 1: attention probs, thread = (tok, h); bf16 A-fragments ----
    {
        int tok = tid >> 2, h = tid & 3;
        int n = nb + tok;
        int th = hour[n];
        const float4* EUp = (const float4*)(EU_s + h * 24);
        const float4* ETp = (const float4*)(ET + th * 96 + h * 24);
        const int4*   mp  = (const int4*)(hour_mask + (long long)n * 24);
        float p[24]; float ssum = 0.f;
        #pragma unroll
        for (int q = 0; q < 6; ++q) {
            float4 e = EUp[q]; float4 f = ETp[q]; int4 m = mp[q];
            float v0 = (m.x != 0) ? 0.f : e.x * f.x;
            float v1 = (m.y != 0) ? 0.f : e.y * f.y;
            float v2 = (m.z != 0) ? 0.f : e.z * f.z;
            float v3 = (m.w != 0) ? 0.f : e.w * f.w;
            p[q*4+0] = v0; p[q*4+1] = v1; p[q*4+2] = v2; p[q*4+3] = v3;
            ssum += (v0 + v1) + (v2 + v3);
        }
        float r = 1.0f / ssum;
        int mt = tok >> 4, tl = tok & 15;
        #pragma unroll
        for (int tp = 0; tp < 12; ++tp) {
            int ht = h * 24 + tp * 2;         // even; pair (ht, ht+1)
            unsigned pack = packbf(p[tp*2] * r, p[tp*2+1] * r);
            int kt = ht >> 5, lg = (ht >> 3) & 3, jh = (ht & 7) >> 1;
            ((unsigned*)A_lds)[((kt * 4 + mt) * 64 + tl + 16 * lg) * 4 + jh] = pack;
        }
    }
    __syncthreads();
    // ---- phase 2: wave w: 4 M-tiles x 4 N-tiles x 3 K-chunks of 16x16x32 ----
    int w = tid >> 6, l = tid & 63;
    const int4* Bg = (const int4*)(ws + VWB_OFF);
    bf16x8 afr[3][4], bfr[3][4];
    #pragma unroll
    for (int kt = 0; kt < 3; ++kt)
        #pragma unroll
        for (int q = 0; q < 4; ++q) {
            afr[kt][q] = __builtin_bit_cast(bf16x8, A_lds[(kt * 4 + q) * 64 + l]);
            bfr[kt][q] = __builtin_bit_cast(bf16x8, Bg[(kt * 16 + w * 4 + q) * 64 + l]);
        }
    f32x4 acc[4][4];
    #pragma unroll
    for (int mt = 0; mt < 4; ++mt)
        #pragma unroll
        for (int q = 0; q < 4; ++q) acc[mt][q] = (f32x4)0.f;
    #pragma unroll
    for (int kt = 0; kt < 3; ++kt)
        #pragma unroll
        for (int mt = 0; mt < 4; ++mt)
            #pragma unroll
            for (int q = 0; q < 4; ++q)
                acc[mt][q] = __builtin_amdgcn_mfma_f32_16x16x32_bf16(
                    afr[kt][mt], bfr[kt][q], acc[mt][q], 0, 0, 0);
    // ---- epilogue: + bu, store (D: col=l&15, row=(l>>4)*4+reg) ----
    int colb = w * 64 + (l & 15);
    float buv[4];
    #pragma unroll
    for (int q = 0; q < 4; ++q) buv[q] = bu[colb + q * 16];
    int row0 = nb + (l >> 4) * 4;
    #pragma unroll
    for (int mt = 0; mt < 4; ++mt)
        #pragma unroll
        for (int q = 0; q < 4; ++q) {
            float* op = out + (size_t)(row0 + mt * 16) * 256 + colb + q * 16;
            #pragma unroll
            for (int r = 0; r < 4; ++r)
                op[(size_t)r * 256] = acc[mt][q][r] + buv[q];
        }
}

extern "C" void kernel_launch(void* const* d_in, const int* in_sizes, int n_in,
                              void* d_out, int out_size, void* d_ws, size_t ws_size,
                              hipStream_t stream)
{
    const float* ts        = (const float*)d_in[0];
    const int*   user      = (const int*)  d_in[1];
    const int*   hour      = (const int*)  d_in[2];
    const int*   hour_mask = (const int*)  d_in[3];
    const float* user_pref = (const float*)d_in[4];
    const float* Wq        = (const float*)d_in[5];
    const float* bq        = (const float*)d_in[6];
    const float* Wk        = (const float*)d_in[7];
    const float* bk        = (const float*)d_in[8];
    const float* Wv        = (const float*)d_in[9];
    const float* bv        = (const float*)d_in[10];
    const float* Wu        = (const float*)d_in[11];
    const float* bu        = (const float*)d_in[12];
    float* ws  = (float*)d_ws;
    float* out = (float*)d_out;

    hipLaunchKernelGGL(precomp, dim3(16), dim3(256), 0, stream,
                       ts, user, user_pref, Wq, bq, Wk, bk, Wv, bv, Wu, ws);
    hipLaunchKernelGGL(attn_mfma, dim3(512), dim3(256), 0, stream,
                       hour, hour_mask, ws, bu, out);
}